// Round 1
// baseline (120.452 us; speedup 1.0000x reference)
//
#include <hip/hip_runtime.h>
#include <math.h>

static constexpr int BATCH = 32;
static constexpr int SEQ   = 4096;
static constexpr int HID   = 1024;
static constexpr int PSTRIDE = HID + 8;   // ctx[1024] + m + l (+pad, keeps 16B alignment)

// -------- Pass 1: fused scores + online-softmax context partials --------
// grid = BATCH*NCHUNK blocks, 256 threads (4 waves).
// Each wave streams RPW consecutive rows of enc[b]; each lane holds 16 floats
// of the row (4 x float4) used BOTH for the dot product and the context FMA.
template<int NCHUNK>
__global__ __launch_bounds__(256)
void attn_fused_pass1(const float* __restrict__ enc,
                      const float* __restrict__ dec,
                      float* __restrict__ raw_scores,   // [B,S] = weights region of d_out
                      float* __restrict__ partials)     // [B*NCHUNK][PSTRIDE]
{
    constexpr int RC  = SEQ / NCHUNK;   // rows per chunk
    constexpr int RPW = RC / 4;         // rows per wave
    const int b     = blockIdx.x / NCHUNK;
    const int chunk = blockIdx.x % NCHUNK;
    const int tid   = threadIdx.x;
    const int w     = tid >> 6;
    const int lane  = tid & 63;

    __shared__ float s_dec[HID];
    __shared__ float s_ctx[4][HID];
    __shared__ float s_m[4], s_l[4];

    // stage dec[b] (4 KB) then keep this lane's 16-float fragment in registers
    ((float4*)s_dec)[tid] = ((const float4*)(dec + (size_t)b * HID))[tid];
    __syncthreads();
    const float4* sd = (const float4*)s_dec;
    const float4 d0 = sd[lane], d1 = sd[lane + 64], d2 = sd[lane + 128], d3 = sd[lane + 192];

    float m = -INFINITY, l = 0.f;
    float4 c0 = make_float4(0.f, 0.f, 0.f, 0.f);
    float4 c1 = c0, c2 = c0, c3 = c0;

    const int row0 = chunk * RC + w * RPW;
    const float4* base = (const float4*)(enc + ((size_t)b * SEQ + row0) * HID);
    float* sout = raw_scores + (size_t)b * SEQ + row0;

    for (int r = 0; r < RPW; ++r) {
        const float4* rp = base + (size_t)r * (HID / 4);
        const float4 e0 = rp[lane];
        const float4 e1 = rp[lane + 64];
        const float4 e2 = rp[lane + 128];
        const float4 e3 = rp[lane + 192];

        float t = e0.x*d0.x + e0.y*d0.y + e0.z*d0.z + e0.w*d0.w;
        t      += e1.x*d1.x + e1.y*d1.y + e1.z*d1.z + e1.w*d1.w;
        t      += e2.x*d2.x + e2.y*d2.y + e2.z*d2.z + e2.w*d2.w;
        t      += e3.x*d3.x + e3.y*d3.y + e3.z*d3.z + e3.w*d3.w;
        #pragma unroll
        for (int off = 32; off > 0; off >>= 1) t += __shfl_xor(t, off, 64);

        if (lane == 0) sout[r] = t;     // raw score; normalized in pass 2

        if (t > m) {                    // wave-uniform branch
            const float sc = __expf(m - t);   // m=-inf first time -> 0
            l *= sc;
            c0.x*=sc; c0.y*=sc; c0.z*=sc; c0.w*=sc;
            c1.x*=sc; c1.y*=sc; c1.z*=sc; c1.w*=sc;
            c2.x*=sc; c2.y*=sc; c2.z*=sc; c2.w*=sc;
            c3.x*=sc; c3.y*=sc; c3.z*=sc; c3.w*=sc;
            m = t;
        }
        const float p = __expf(t - m);
        l += p;
        c0.x += p*e0.x; c0.y += p*e0.y; c0.z += p*e0.z; c0.w += p*e0.w;
        c1.x += p*e1.x; c1.y += p*e1.y; c1.z += p*e1.z; c1.w += p*e1.w;
        c2.x += p*e2.x; c2.y += p*e2.y; c2.z += p*e2.z; c2.w += p*e2.w;
        c3.x += p*e3.x; c3.y += p*e3.y; c3.z += p*e3.z; c3.w += p*e3.w;
    }

    // ---- combine the 4 waves of this block ----
    if (lane == 0) { s_m[w] = m; s_l[w] = l; }
    __syncthreads();
    const float mg = fmaxf(fmaxf(s_m[0], s_m[1]), fmaxf(s_m[2], s_m[3]));
    const float f  = __expf(m - mg);   // wave-uniform
    float4* sc4 = (float4*)s_ctx[w];
    float4 t0 = c0, t1 = c1, t2 = c2, t3 = c3;
    t0.x*=f; t0.y*=f; t0.z*=f; t0.w*=f;
    t1.x*=f; t1.y*=f; t1.z*=f; t1.w*=f;
    t2.x*=f; t2.y*=f; t2.z*=f; t2.w*=f;
    t3.x*=f; t3.y*=f; t3.z*=f; t3.w*=f;
    sc4[lane]       = t0;
    sc4[lane + 64]  = t1;
    sc4[lane + 128] = t2;
    sc4[lane + 192] = t3;
    __syncthreads();

    float lb = 0.f;
    #pragma unroll
    for (int i = 0; i < 4; ++i) lb += s_l[i] * __expf(s_m[i] - mg);

    float* pout = partials + (size_t)(b * NCHUNK + chunk) * PSTRIDE;
    const float4 v0 = ((const float4*)s_ctx[0])[tid];
    const float4 v1 = ((const float4*)s_ctx[1])[tid];
    const float4 v2 = ((const float4*)s_ctx[2])[tid];
    const float4 v3 = ((const float4*)s_ctx[3])[tid];
    float4 sum;
    sum.x = (v0.x + v1.x) + (v2.x + v3.x);
    sum.y = (v0.y + v1.y) + (v2.y + v3.y);
    sum.z = (v0.z + v1.z) + (v2.z + v3.z);
    sum.w = (v0.w + v1.w) + (v2.w + v3.w);
    ((float4*)pout)[tid] = sum;
    if (tid == 0) { pout[HID] = mg; pout[HID + 1] = lb; }
}

// -------- Pass 2: cross-chunk combine + weights normalization --------
template<int NCHUNK>
__global__ __launch_bounds__(256)
void attn_pass2(const float* __restrict__ partials,
                float* __restrict__ out_ctx,    // [B,H]
                float* __restrict__ weights)    // [B,S] in-place raw->softmax
{
    const int b   = blockIdx.x;
    const int tid = threadIdx.x;
    __shared__ float sm[NCHUNK], sl[NCHUNK];
    if (tid < NCHUNK) {
        const float* p = partials + (size_t)(b * NCHUNK + tid) * PSTRIDE;
        sm[tid] = p[HID];
        sl[tid] = p[HID + 1];
    }
    __syncthreads();

    float mg = -INFINITY;
    #pragma unroll
    for (int c = 0; c < NCHUNK; ++c) mg = fmaxf(mg, sm[c]);
    float lg = 0.f;
    #pragma unroll
    for (int c = 0; c < NCHUNK; ++c) lg += sl[c] * __expf(sm[c] - mg);
    const float inv = 1.f / lg;

    // context: one float4 per thread (H = 1024 = 256 float4)
    float4 acc = make_float4(0.f, 0.f, 0.f, 0.f);
    #pragma unroll 4
    for (int c = 0; c < NCHUNK; ++c) {
        const float4* p4 = (const float4*)(partials + (size_t)(b * NCHUNK + c) * PSTRIDE);
        const float fc = __expf(sm[c] - mg);
        const float4 v = p4[tid];
        acc.x += fc * v.x; acc.y += fc * v.y; acc.z += fc * v.z; acc.w += fc * v.w;
    }
    acc.x *= inv; acc.y *= inv; acc.z *= inv; acc.w *= inv;
    ((float4*)(out_ctx + (size_t)b * HID))[tid] = acc;

    // weights: normalize raw scores in place
    float* wrow = weights + (size_t)b * SEQ;
    for (int s = tid; s < SEQ; s += 256) {
        wrow[s] = __expf(wrow[s] - mg) * inv;
    }
}

extern "C" void kernel_launch(void* const* d_in, const int* in_sizes, int n_in,
                              void* d_out, int out_size, void* d_ws, size_t ws_size,
                              hipStream_t stream) {
    const float* hidden = (const float*)d_in[0];          // [2, 32, 1024]
    const float* enc    = (const float*)d_in[1];          // [32, 4096, 1024]
    const float* dec    = hidden + (size_t)BATCH * HID;   // hidden[-1] -> [32, 1024]

    float* out     = (float*)d_out;
    float* ctx_out = out;                                 // [32, 1024]
    float* w_out   = out + (size_t)BATCH * HID;           // [32, 4096]
    float* partials = (float*)d_ws;

#define LAUNCH_NC(NC)                                                              \
    do {                                                                           \
        attn_fused_pass1<NC><<<BATCH * NC, 256, 0, stream>>>(enc, dec, w_out,      \
                                                             partials);            \
        attn_pass2<NC><<<BATCH, 256, 0, stream>>>(partials, ctx_out, w_out);       \
    } while (0)

    const size_t per_chunk_bytes = (size_t)BATCH * PSTRIDE * sizeof(float);
    if      (ws_size >= 32 * per_chunk_bytes) LAUNCH_NC(32);
    else if (ws_size >= 16 * per_chunk_bytes) LAUNCH_NC(16);
    else if (ws_size >=  8 * per_chunk_bytes) LAUNCH_NC(8);
    else if (ws_size >=  4 * per_chunk_bytes) LAUNCH_NC(4);
    else if (ws_size >=  2 * per_chunk_bytes) LAUNCH_NC(2);
    else                                      LAUNCH_NC(1);
#undef LAUNCH_NC
}

// Round 2
// 115.956 us; speedup vs baseline: 1.0388x; 1.0388x over previous
//
#include <hip/hip_runtime.h>
#include <math.h>

static constexpr int BATCH = 32;
static constexpr int SEQ   = 4096;
static constexpr int HID   = 1024;
static constexpr int PSTRIDE = HID + 8;   // ctx[1024] + m + l (+pad, keeps 16B alignment)

// -------- Pass 1: fused scores + online-softmax context partials --------
// grid = BATCH*NCHUNK blocks, 256 threads (4 waves).
// Each wave streams RPW consecutive rows of enc[b], TWO rows per iteration
// (independent reduce chains, 8 KB of loads in flight per wave).
template<int NCHUNK>
__global__ __launch_bounds__(256, 4)
void attn_fused_pass1(const float* __restrict__ enc,
                      const float* __restrict__ dec,
                      float* __restrict__ raw_scores,   // [B,S] = weights region of d_out
                      float* __restrict__ partials)     // [B*NCHUNK][PSTRIDE]
{
    constexpr int RC  = SEQ / NCHUNK;   // rows per chunk
    constexpr int RPW = RC / 4;         // rows per wave (even for all NCHUNK here)
    const int b     = blockIdx.x / NCHUNK;
    const int chunk = blockIdx.x % NCHUNK;
    const int tid   = threadIdx.x;
    const int w     = tid >> 6;
    const int lane  = tid & 63;

    __shared__ float s_dec[HID];
    __shared__ float s_ctx[4][HID];
    __shared__ float s_m[4], s_l[4];

    // stage dec[b] (4 KB) then keep this lane's 16-float fragment in registers
    ((float4*)s_dec)[tid] = ((const float4*)(dec + (size_t)b * HID))[tid];
    __syncthreads();
    const float4* sd = (const float4*)s_dec;
    const float4 d0 = sd[lane], d1 = sd[lane + 64], d2 = sd[lane + 128], d3 = sd[lane + 192];

    float m = -INFINITY, l = 0.f;
    float4 c0 = make_float4(0.f, 0.f, 0.f, 0.f);
    float4 c1 = c0, c2 = c0, c3 = c0;

    const int row0 = chunk * RC + w * RPW;
    const float4* base = (const float4*)(enc + ((size_t)b * SEQ + row0) * HID);
    float* sout = raw_scores + (size_t)b * SEQ + row0;

    for (int r = 0; r < RPW; r += 2) {
        const float4* rpA = base + (size_t)r * (HID / 4);
        const float4* rpB = rpA + (HID / 4);
        const float4 a0 = rpA[lane];
        const float4 a1 = rpA[lane + 64];
        const float4 a2 = rpA[lane + 128];
        const float4 a3 = rpA[lane + 192];
        const float4 b0 = rpB[lane];
        const float4 b1 = rpB[lane + 64];
        const float4 b2 = rpB[lane + 128];
        const float4 b3 = rpB[lane + 192];

        // treed dot partials: 4 independent 4-FMA chains each, then 2 adds
        float tA0 = a0.x*d0.x + a0.y*d0.y + a0.z*d0.z + a0.w*d0.w;
        float tA1 = a1.x*d1.x + a1.y*d1.y + a1.z*d1.z + a1.w*d1.w;
        float tA2 = a2.x*d2.x + a2.y*d2.y + a2.z*d2.z + a2.w*d2.w;
        float tA3 = a3.x*d3.x + a3.y*d3.y + a3.z*d3.z + a3.w*d3.w;
        float tB0 = b0.x*d0.x + b0.y*d0.y + b0.z*d0.z + b0.w*d0.w;
        float tB1 = b1.x*d1.x + b1.y*d1.y + b1.z*d1.z + b1.w*d1.w;
        float tB2 = b2.x*d2.x + b2.y*d2.y + b2.z*d2.z + b2.w*d2.w;
        float tB3 = b3.x*d3.x + b3.y*d3.y + b3.z*d3.z + b3.w*d3.w;
        float tA = (tA0 + tA1) + (tA2 + tA3);
        float tB = (tB0 + tB1) + (tB2 + tB3);

        // two independent 6-step reduce chains, interleaved
        #pragma unroll
        for (int off = 32; off > 0; off >>= 1) {
            tA += __shfl_xor(tA, off, 64);
            tB += __shfl_xor(tB, off, 64);
        }

        if (lane == 0) {
            float2 sc2; sc2.x = tA; sc2.y = tB;
            *(float2*)(sout + r) = sc2;      // raw scores; normalized in pass 2
        }

        const float mn = fmaxf(m, fmaxf(tA, tB));
        if (mn > m) {                        // wave-uniform, rare after warm-up
            const float sc = __expf(m - mn); // m=-inf first time -> 0
            l *= sc;
            c0.x*=sc; c0.y*=sc; c0.z*=sc; c0.w*=sc;
            c1.x*=sc; c1.y*=sc; c1.z*=sc; c1.w*=sc;
            c2.x*=sc; c2.y*=sc; c2.z*=sc; c2.w*=sc;
            c3.x*=sc; c3.y*=sc; c3.z*=sc; c3.w*=sc;
            m = mn;
        }
        const float pA = __expf(tA - m);
        const float pB = __expf(tB - m);
        l += pA + pB;
        c0.x += pA*a0.x + pB*b0.x; c0.y += pA*a0.y + pB*b0.y;
        c0.z += pA*a0.z + pB*b0.z; c0.w += pA*a0.w + pB*b0.w;
        c1.x += pA*a1.x + pB*b1.x; c1.y += pA*a1.y + pB*b1.y;
        c1.z += pA*a1.z + pB*b1.z; c1.w += pA*a1.w + pB*b1.w;
        c2.x += pA*a2.x + pB*b2.x; c2.y += pA*a2.y + pB*b2.y;
        c2.z += pA*a2.z + pB*b2.z; c2.w += pA*a2.w + pB*b2.w;
        c3.x += pA*a3.x + pB*b3.x; c3.y += pA*a3.y + pB*b3.y;
        c3.z += pA*a3.z + pB*b3.z; c3.w += pA*a3.w + pB*b3.w;
    }

    // ---- combine the 4 waves of this block ----
    if (lane == 0) { s_m[w] = m; s_l[w] = l; }
    __syncthreads();
    const float mg = fmaxf(fmaxf(s_m[0], s_m[1]), fmaxf(s_m[2], s_m[3]));
    const float f  = __expf(m - mg);   // wave-uniform
    float4* sc4 = (float4*)s_ctx[w];
    float4 t0 = c0, t1 = c1, t2 = c2, t3 = c3;
    t0.x*=f; t0.y*=f; t0.z*=f; t0.w*=f;
    t1.x*=f; t1.y*=f; t1.z*=f; t1.w*=f;
    t2.x*=f; t2.y*=f; t2.z*=f; t2.w*=f;
    t3.x*=f; t3.y*=f; t3.z*=f; t3.w*=f;
    sc4[lane]       = t0;
    sc4[lane + 64]  = t1;
    sc4[lane + 128] = t2;
    sc4[lane + 192] = t3;
    __syncthreads();

    float lb = 0.f;
    #pragma unroll
    for (int i = 0; i < 4; ++i) lb += s_l[i] * __expf(s_m[i] - mg);

    float* pout = partials + (size_t)(b * NCHUNK + chunk) * PSTRIDE;
    const float4 v0 = ((const float4*)s_ctx[0])[tid];
    const float4 v1 = ((const float4*)s_ctx[1])[tid];
    const float4 v2 = ((const float4*)s_ctx[2])[tid];
    const float4 v3 = ((const float4*)s_ctx[3])[tid];
    float4 sum;
    sum.x = (v0.x + v1.x) + (v2.x + v3.x);
    sum.y = (v0.y + v1.y) + (v2.y + v3.y);
    sum.z = (v0.z + v1.z) + (v2.z + v3.z);
    sum.w = (v0.w + v1.w) + (v2.w + v3.w);
    ((float4*)pout)[tid] = sum;
    if (tid == 0) { pout[HID] = mg; pout[HID + 1] = lb; }
}

// -------- Pass 2: cross-chunk combine + weights normalization --------
template<int NCHUNK>
__global__ __launch_bounds__(256)
void attn_pass2(const float* __restrict__ partials,
                float* __restrict__ out_ctx,    // [B,H]
                float* __restrict__ weights)    // [B,S] in-place raw->softmax
{
    const int b   = blockIdx.x;
    const int tid = threadIdx.x;
    __shared__ float sm[NCHUNK], sl[NCHUNK];
    if (tid < NCHUNK) {
        const float* p = partials + (size_t)(b * NCHUNK + tid) * PSTRIDE;
        sm[tid] = p[HID];
        sl[tid] = p[HID + 1];
    }
    __syncthreads();

    float mg = -INFINITY;
    #pragma unroll
    for (int c = 0; c < NCHUNK; ++c) mg = fmaxf(mg, sm[c]);
    float lg = 0.f;
    #pragma unroll
    for (int c = 0; c < NCHUNK; ++c) lg += sl[c] * __expf(sm[c] - mg);
    const float inv = 1.f / lg;

    // context: one float4 per thread (H = 1024 = 256 float4)
    float4 acc = make_float4(0.f, 0.f, 0.f, 0.f);
    #pragma unroll 4
    for (int c = 0; c < NCHUNK; ++c) {
        const float4* p4 = (const float4*)(partials + (size_t)(b * NCHUNK + c) * PSTRIDE);
        const float fc = __expf(sm[c] - mg);
        const float4 v = p4[tid];
        acc.x += fc * v.x; acc.y += fc * v.y; acc.z += fc * v.z; acc.w += fc * v.w;
    }
    acc.x *= inv; acc.y *= inv; acc.z *= inv; acc.w *= inv;
    ((float4*)(out_ctx + (size_t)b * HID))[tid] = acc;

    // weights: normalize raw scores in place
    float* wrow = weights + (size_t)b * SEQ;
    #pragma unroll 4
    for (int s = tid; s < SEQ; s += 256) {
        wrow[s] = __expf(wrow[s] - mg) * inv;
    }
}

extern "C" void kernel_launch(void* const* d_in, const int* in_sizes, int n_in,
                              void* d_out, int out_size, void* d_ws, size_t ws_size,
                              hipStream_t stream) {
    const float* hidden = (const float*)d_in[0];          // [2, 32, 1024]
    const float* enc    = (const float*)d_in[1];          // [32, 4096, 1024]
    const float* dec    = hidden + (size_t)BATCH * HID;   // hidden[-1] -> [32, 1024]

    float* out     = (float*)d_out;
    float* ctx_out = out;                                 // [32, 1024]
    float* w_out   = out + (size_t)BATCH * HID;           // [32, 4096]
    float* partials = (float*)d_ws;

#define LAUNCH_NC(NC)                                                              \
    do {                                                                           \
        attn_fused_pass1<NC><<<BATCH * NC, 256, 0, stream>>>(enc, dec, w_out,      \
                                                             partials);            \
        attn_pass2<NC><<<BATCH, 256, 0, stream>>>(partials, ctx_out, w_out);       \
    } while (0)

    const size_t per_chunk_bytes = (size_t)BATCH * PSTRIDE * sizeof(float);
    if      (ws_size >= 32 * per_chunk_bytes) LAUNCH_NC(32);
    else if (ws_size >= 16 * per_chunk_bytes) LAUNCH_NC(16);
    else if (ws_size >=  8 * per_chunk_bytes) LAUNCH_NC(8);
    else if (ws_size >=  4 * per_chunk_bytes) LAUNCH_NC(4);
    else if (ws_size >=  2 * per_chunk_bytes) LAUNCH_NC(2);
    else                                      LAUNCH_NC(1);
#undef LAUNCH_NC
}